// Round 1
// baseline (260.047 us; speedup 1.0000x reference)
//
#include <hip/hip_runtime.h>

// ---------------------------------------------------------------------------
// HilbertAttention: qkv-proj (fp16 MFMA) -> segmented attention -> out-proj
// B=4, M=4096, D=1024, H=16, hd=64, SEG=128, DIL=2 -> S=32 segments
// perm is closed-form serpentine on a 64x64 grid (g==64 exactly).
// Reference does NOT un-permute attention output.
// ---------------------------------------------------------------------------

typedef _Float16 f16x8 __attribute__((ext_vector_type(8)));
typedef _Float16 f16x4 __attribute__((ext_vector_type(4)));
typedef float f32x4 __attribute__((ext_vector_type(4)));

__device__ __forceinline__ int hperm(int i) {
  int r = i >> 6, c = i & 63;
  return (r << 6) | ((r & 1) ? (63 - c) : c);
}

__device__ __forceinline__ void gload_lds16(const _Float16* g, _Float16* l) {
  __builtin_amdgcn_global_load_lds(
      (const __attribute__((address_space(1))) void*)g,
      (__attribute__((address_space(3))) void*)l, 16, 0, 0);
}

// -------------------------- cast fp32 -> fp16 ------------------------------
__global__ __launch_bounds__(256) void cast_f32_f16(
    const float* __restrict__ s, _Float16* __restrict__ d, int n4) {
  int i = blockIdx.x * 256 + threadIdx.x;
  if (i >= n4) return;
  float4 v = ((const float4*)s)[i];
  f16x4 o;
  o[0] = (_Float16)v.x;
  o[1] = (_Float16)v.y;
  o[2] = (_Float16)v.z;
  o[3] = (_Float16)v.w;
  *(f16x4*)&d[(size_t)i * 4] = o;
}

// ------------------- C[M][N] = A[M][K] * B[N][K]^T (fp16 in, fp32 acc) -----
// 128x128 tile, BK=32, 4 waves each computing a 64x64 quadrant (4x4 frags).
template <typename OutT>
__global__ __launch_bounds__(256) void gemm_nt(
    const _Float16* __restrict__ A, const _Float16* __restrict__ B,
    OutT* __restrict__ C, int M, int N, int K) {
  (void)M;
  __shared__ _Float16 As[128 * 32];
  __shared__ _Float16 Bs[128 * 32];
  const int t = threadIdx.x;
  const int lane = t & 63, wave = t >> 6;
  const int wr = (wave >> 1) * 64, wc = (wave & 1) * 64;
  const int lr = lane & 15, lk = (lane >> 4) * 8;
  const int bm = blockIdx.x, bn = blockIdx.y;
  const int srow = t >> 2, scol = (t & 3) * 8;

  const _Float16* Ab = A + (size_t)bm * 128 * K + (size_t)srow * K + scol;
  const _Float16* Bb = B + (size_t)bn * 128 * K + (size_t)srow * K + scol;
  _Float16* as_dst = &As[srow * 32 + scol];
  _Float16* bs_dst = &Bs[srow * 32 + scol];

  f32x4 acc[4][4] = {};
  for (int k0 = 0; k0 < K; k0 += 32) {
    gload_lds16(Ab + k0, as_dst);
    gload_lds16(Ab + k0 + (size_t)64 * K, as_dst + 64 * 32);
    gload_lds16(Bb + k0, bs_dst);
    gload_lds16(Bb + k0 + (size_t)64 * K, bs_dst + 64 * 32);
    __syncthreads();
    f16x8 a[4], b[4];
#pragma unroll
    for (int m = 0; m < 4; m++)
      a[m] = *(const f16x8*)&As[(wr + m * 16 + lr) * 32 + lk];
#pragma unroll
    for (int n = 0; n < 4; n++)
      b[n] = *(const f16x8*)&Bs[(wc + n * 16 + lr) * 32 + lk];
#pragma unroll
    for (int m = 0; m < 4; m++)
#pragma unroll
      for (int n = 0; n < 4; n++)
        acc[m][n] =
            __builtin_amdgcn_mfma_f32_16x16x32_f16(a[m], b[n], acc[m][n], 0, 0, 0);
    __syncthreads();
  }
  // Epilogue: C/D layout col=lane&15, row=(lane>>4)*4+j  [m89/m91 verified]
#pragma unroll
  for (int m = 0; m < 4; m++) {
    int row0 = bm * 128 + wr + m * 16 + (lane >> 4) * 4;
#pragma unroll
    for (int n = 0; n < 4; n++) {
      int col = bn * 128 + wc + n * 16 + lr;
#pragma unroll
      for (int j = 0; j < 4; j++)
        C[(size_t)(row0 + j) * N + col] = (OutT)acc[m][n][j];
    }
  }
}

// ----------------------------- attention -----------------------------------
// One block per (b,h,s). Q:128x64, K,V: 64x64 (dilated by 2 within segment).
// LDS rows padded to stride 72 halves (144B) to break 128B-stride conflicts.
#define STRD 72

__global__ __launch_bounds__(256) void hilbert_attn(
    const _Float16* __restrict__ qkv, _Float16* __restrict__ aout) {
  __shared__ _Float16 Qs[128 * STRD];
  __shared__ _Float16 Ks[64 * STRD];
  __shared__ _Float16 Vt[64 * STRD];  // transposed: Vt[d][j] = V[j][d]
  __shared__ _Float16 Ps[128 * STRD];
  const int blk = blockIdx.x;
  const int s = blk & 31, h = (blk >> 5) & 15, b = blk >> 9;
  const int t = threadIdx.x, lane = t & 63, wave = t >> 6;
  const int lr = lane & 15, lg = lane >> 4, lk = lg * 8;
  const size_t base = (size_t)b * 4096 * 3072;
  const int col = (t & 7) * 8, rr = t >> 3;

  // ---- stage Q (gathered via perm), K,V (dilated gather) ----
#pragma unroll
  for (int i = 0; i < 4; i++) {
    int m = i * 32 + rr;
    int p = hperm(s * 128 + m);
    *(f16x8*)&Qs[m * STRD + col] =
        *(const f16x8*)&qkv[base + (size_t)p * 3072 + h * 64 + col];
  }
#pragma unroll
  for (int i = 0; i < 2; i++) {
    int j = i * 32 + rr;
    int p = hperm(s * 128 + 2 * j);
    *(f16x8*)&Ks[j * STRD + col] =
        *(const f16x8*)&qkv[base + (size_t)p * 3072 + 1024 + h * 64 + col];
    f16x8 vv = *(const f16x8*)&qkv[base + (size_t)p * 3072 + 2048 + h * 64 + col];
#pragma unroll
    for (int e = 0; e < 8; e++) Vt[(col + e) * STRD + j] = vv[e];
  }
  __syncthreads();

  // ---- S = scale * Q K^T  (each wave: 32 rows x 64 cols = 2x4 frags) ----
  f32x4 accs[2][4] = {};
#pragma unroll
  for (int kk = 0; kk < 2; kk++) {
    f16x8 a[2], bb[4];
#pragma unroll
    for (int m = 0; m < 2; m++)
      a[m] = *(const f16x8*)&Qs[(wave * 32 + m * 16 + lr) * STRD + kk * 32 + lk];
#pragma unroll
    for (int n = 0; n < 4; n++)
      bb[n] = *(const f16x8*)&Ks[(n * 16 + lr) * STRD + kk * 32 + lk];
#pragma unroll
    for (int m = 0; m < 2; m++)
#pragma unroll
      for (int n = 0; n < 4; n++)
        accs[m][n] =
            __builtin_amdgcn_mfma_f32_16x16x32_f16(a[m], bb[n], accs[m][n], 0, 0, 0);
  }

  // ---- softmax fully in registers: a row's 64 scores live in one 16-lane
  // group (lanes lg*16..lg*16+15) x 4 regs (n). shfl_xor width-16 reduce. ----
#pragma unroll
  for (int m = 0; m < 2; m++) {
#pragma unroll
    for (int j = 0; j < 4; j++) {
      float sc0 = accs[m][0][j] * 0.125f;
      float sc1 = accs[m][1][j] * 0.125f;
      float sc2 = accs[m][2][j] * 0.125f;
      float sc3 = accs[m][3][j] * 0.125f;
      float mx = fmaxf(fmaxf(sc0, sc1), fmaxf(sc2, sc3));
#pragma unroll
      for (int d = 1; d < 16; d <<= 1) mx = fmaxf(mx, __shfl_xor(mx, d, 16));
      float e0 = __expf(sc0 - mx), e1 = __expf(sc1 - mx);
      float e2 = __expf(sc2 - mx), e3 = __expf(sc3 - mx);
      float sum = (e0 + e1) + (e2 + e3);
#pragma unroll
      for (int d = 1; d < 16; d <<= 1) sum += __shfl_xor(sum, d, 16);
      float inv = 1.0f / sum;
      int row = wave * 32 + m * 16 + lg * 4 + j;
      Ps[row * STRD + 0 * 16 + lr] = (_Float16)(e0 * inv);
      Ps[row * STRD + 1 * 16 + lr] = (_Float16)(e1 * inv);
      Ps[row * STRD + 2 * 16 + lr] = (_Float16)(e2 * inv);
      Ps[row * STRD + 3 * 16 + lr] = (_Float16)(e3 * inv);
    }
  }
  __syncthreads();

  // ---- O = P V  (as P * (V^T)^T, NT form with Vt) ----
  f32x4 acco[2][4] = {};
#pragma unroll
  for (int kk = 0; kk < 2; kk++) {
    f16x8 a[2], bb[4];
#pragma unroll
    for (int m = 0; m < 2; m++)
      a[m] = *(const f16x8*)&Ps[(wave * 32 + m * 16 + lr) * STRD + kk * 32 + lk];
#pragma unroll
    for (int n = 0; n < 4; n++)
      bb[n] = *(const f16x8*)&Vt[(n * 16 + lr) * STRD + kk * 32 + lk];
#pragma unroll
    for (int m = 0; m < 2; m++)
#pragma unroll
      for (int n = 0; n < 4; n++)
        acco[m][n] =
            __builtin_amdgcn_mfma_f32_16x16x32_f16(a[m], bb[n], acco[m][n], 0, 0, 0);
  }

  // ---- store O in PERMUTED row order (reference does not un-permute) ----
  const size_t orow0 = (size_t)b * 4096 + s * 128;
#pragma unroll
  for (int m = 0; m < 2; m++) {
#pragma unroll
    for (int n = 0; n < 4; n++) {
#pragma unroll
      for (int j = 0; j < 4; j++) {
        size_t row = orow0 + wave * 32 + m * 16 + lg * 4 + j;
        aout[row * 1024 + h * 64 + n * 16 + lr] = (_Float16)acco[m][n][j];
      }
    }
  }
}

// ---------------------------------------------------------------------------
extern "C" void kernel_launch(void* const* d_in, const int* in_sizes, int n_in,
                              void* d_out, int out_size, void* d_ws, size_t ws_size,
                              hipStream_t stream) {
  const float* x = (const float*)d_in[0];      // (4,4096,1024)
  const float* w_qkv = (const float*)d_in[1];  // (3072,1024)
  const float* w_out = (const float*)d_in[2];  // (1024,1024)
  float* out = (float*)d_out;                  // (4,4096,1024) fp32
  char* ws = (char*)d_ws;

  _Float16* xh = (_Float16*)(ws + 0);                       // 33,554,432 B
  _Float16* wqh = (_Float16*)(ws + (size_t)33554432);       //  6,291,456 B
  _Float16* woh = (_Float16*)(ws + (size_t)39845888);       //  2,097,152 B
  _Float16* qkvh = (_Float16*)(ws + (size_t)41943040);      // 100,663,296 B
  _Float16* atth = (_Float16*)(ws + (size_t)142606336);     // 33,554,432 B

  cast_f32_f16<<<16384, 256, 0, stream>>>(x, xh, 4194304);
  cast_f32_f16<<<3072, 256, 0, stream>>>(w_qkv, wqh, 786432);
  cast_f32_f16<<<1024, 256, 0, stream>>>(w_out, woh, 262144);

  gemm_nt<_Float16><<<dim3(128, 24), 256, 0, stream>>>(xh, wqh, qkvh,
                                                       16384, 3072, 1024);
  hilbert_attn<<<2048, 256, 0, stream>>>(qkvh, atth);
  gemm_nt<float><<<dim3(128, 8), 256, 0, stream>>>(atth, woh, out,
                                                   16384, 1024, 1024);
}

// Round 2
// 207.716 us; speedup vs baseline: 1.2519x; 1.2519x over previous
//
#include <hip/hip_runtime.h>

// ---------------------------------------------------------------------------
// HilbertAttention: qkv-proj (fp16 MFMA, 256^2 8-phase) -> segmented attention
// -> out-proj. B=4, M=4096, D=1024, H=16, hd=64, SEG=128, DIL=2 -> S=32.
// perm is closed-form serpentine (g==64). Output stays in permuted row order.
// ---------------------------------------------------------------------------

typedef _Float16 f16x8 __attribute__((ext_vector_type(8)));
typedef _Float16 f16x4 __attribute__((ext_vector_type(4)));
typedef float f32x4 __attribute__((ext_vector_type(4)));

__device__ __forceinline__ int hperm(int i) {
  int r = i >> 6, c = i & 63;
  return (r << 6) | ((r & 1) ? (63 - c) : c);
}

__device__ __forceinline__ void gload_lds16(const _Float16* g, _Float16* l) {
  __builtin_amdgcn_global_load_lds(
      (const __attribute__((address_space(1))) void*)g,
      (__attribute__((address_space(3))) void*)l, 16, 0, 0);
}

// -------------------------- cast fp32 -> fp16 ------------------------------
__global__ __launch_bounds__(256) void cast_f32_f16(
    const float* __restrict__ s, _Float16* __restrict__ d, int n4) {
  int i = blockIdx.x * 256 + threadIdx.x;
  if (i >= n4) return;
  float4 v = ((const float4*)s)[i];
  f16x4 o;
  o[0] = (_Float16)v.x;
  o[1] = (_Float16)v.y;
  o[2] = (_Float16)v.z;
  o[3] = (_Float16)v.w;
  *(f16x4*)&d[(size_t)i * 4] = o;
}

// ---------------- 256x256 8-phase NT GEMM: C = A * B^T ---------------------
// A[M][K], B[N][K] fp16; C fp32-accumulated. BK=64, 512 thr = 8 waves (2Mx4N),
// per-wave 128x64 output. LDS 128 KiB (2 dbuf x (A 32K + B 32K)).
// Swizzle: half_idx ^= ((row&7)<<3)  (16B-slot XOR; 2-way conflicts = free).
// Stage slots: P0/P1 = A(k+1); P2..P5 = B0,B1,A0,A1 of (k+2); P6/P7 = B(k+3).
// vmcnt(4) only at P3/P7 (counted; 2 half-tiles in flight).

#define BAR __builtin_amdgcn_s_barrier()
#define LGKM0                                              \
  do {                                                     \
    asm volatile("s_waitcnt lgkmcnt(0)" ::: "memory");     \
    __builtin_amdgcn_sched_barrier(0);                     \
  } while (0)
#define VM4 asm volatile("s_waitcnt vmcnt(4)" ::: "memory")

#define STG(mat, kt, h, buf)                                               \
  do {                                                                     \
    if ((kt) < NK) {                                                       \
      const _Float16* g_ = ((mat) ? Bg : Ag) + (size_t)(h)*128 * K +       \
                           (size_t)(kt)*64;                                \
      _Float16* d_ = &lds[buf][mat][h][t * 8];                             \
      gload_lds16(g_, d_);                                                 \
      gload_lds16(g_ + (size_t)64 * K, d_ + 4096);                        \
    }                                                                      \
  } while (0)

#define LDA_(buf, mh)                                                      \
  _Pragma("unroll") for (int m = 0; m < 4; m++) {                          \
    const _Float16* p_ = &lds[buf][0][wm][((mh)*64 + m * 16 + lr) * 64];   \
    a[0][m] = *(const f16x8*)(p_ + cx0);                                   \
    a[1][m] = *(const f16x8*)(p_ + cx1);                                   \
  }

#define LDB_(buf, nh)                                                      \
  _Pragma("unroll") for (int nf = 0; nf < 2; nf++) {                       \
    const _Float16* p_ =                                                   \
        &lds[buf][1][wn >> 1][((wn & 1) * 64 + (nh)*32 + nf * 16 + lr) * 64]; \
    b[nh][0][nf] = *(const f16x8*)(p_ + cx0);                              \
    b[nh][1][nf] = *(const f16x8*)(p_ + cx1);                              \
  }

#define MM_(mh, nh)                                                        \
  __builtin_amdgcn_s_setprio(1);                                           \
  _Pragma("unroll") for (int m = 0; m < 4; m++)                            \
      _Pragma("unroll") for (int nf = 0; nf < 2; nf++)                     \
          _Pragma("unroll") for (int ks = 0; ks < 2; ks++) acc[(mh)*4 + m] \
              [(nh)*2 + nf] = __builtin_amdgcn_mfma_f32_16x16x32_f16(      \
                  a[ks][m], b[nh][ks][nf], acc[(mh)*4 + m][(nh)*2 + nf],   \
                  0, 0, 0);                                                \
  __builtin_amdgcn_s_setprio(0);

template <typename OutT>
__global__ __launch_bounds__(512, 2) void gemm_nt_8ph(
    const _Float16* __restrict__ A, const _Float16* __restrict__ B,
    OutT* __restrict__ C, int N, int K, int NB) {
  __shared__ _Float16 lds[2][2][2][8192];  // [dbuf][A/B][half][128*64]
  const int t = threadIdx.x;
  const int lane = t & 63, wave = t >> 6;
  const int wm = wave >> 2, wn = wave & 3;
  const int lr = lane & 15, lg = lane >> 4;

  // XCD-aware bijective swizzle (gridDim.x % 8 == 0 by construction)
  const int nwg = gridDim.x;
  const int id = blockIdx.x;
  const int sw = (id & 7) * (nwg >> 3) + (id >> 3);
  const int bn = sw % NB, bm = sw / NB;

  const size_t arow0 = (size_t)bm * 256;
  const size_t brow0 = (size_t)bn * 256;
  const int NK = K >> 6;

  // staging: thread t covers row (t>>3) [+64 round 2], swizzled source col
  const int sgrow = t >> 3;
  const int sgcol = ((t & 7) * 8) ^ ((sgrow & 7) << 3);
  const _Float16* Ag = A + (arow0 + sgrow) * (size_t)K + sgcol;
  const _Float16* Bg = B + (brow0 + sgrow) * (size_t)K + sgcol;

  // per-lane swizzled ds_read column offsets (row&7 == lr&7 for all frags)
  const int cx0 = (lg * 8) ^ ((lr & 7) << 3);
  const int cx1 = cx0 ^ 32;

  f32x4 acc[8][4] = {};
  f16x8 a[2][4], b[2][2][2];

  // ---- prologue: k0 -> buf0 (A0,A1,B0,B1); k1.B0,B1 -> buf1 ----
  STG(0, 0, 0, 0);
  STG(0, 0, 1, 0);
  STG(1, 0, 0, 0);
  STG(1, 0, 1, 0);
  STG(1, 1, 0, 1);
  STG(1, 1, 1, 1);
  VM4;
  BAR;

  for (int i = 0; i < NK / 2; i++) {
    const int k1 = 2 * i + 1, k2 = 2 * i + 2, k3 = 2 * i + 3;
    // P0: compute buf0 (mh0,nh0)
    LDA_(0, 0); LDB_(0, 0); STG(0, k1, 0, 1); BAR; LGKM0; MM_(0, 0); BAR;
    // P1: (mh0,nh1)
    LDB_(0, 1);             STG(0, k1, 1, 1); BAR; LGKM0; MM_(0, 1); BAR;
    // P2: (mh1,nh1)
    LDA_(0, 1);             STG(1, k2, 0, 0); BAR; LGKM0; MM_(1, 1); BAR;
    // P3: (mh1,nh0)  [no ds_reads]
                            STG(1, k2, 1, 0); VM4; BAR; LGKM0; MM_(1, 0); BAR;
    // P4: compute buf1 (mh0,nh0)
    LDA_(1, 0); LDB_(1, 0); STG(0, k2, 0, 0); BAR; LGKM0; MM_(0, 0); BAR;
    // P5: (mh0,nh1)
    LDB_(1, 1);             STG(0, k2, 1, 0); BAR; LGKM0; MM_(0, 1); BAR;
    // P6: (mh1,nh1)
    LDA_(1, 1);             STG(1, k3, 0, 1); BAR; LGKM0; MM_(1, 1); BAR;
    // P7: (mh1,nh0)
                            STG(1, k3, 1, 1); VM4; BAR; LGKM0; MM_(1, 0); BAR;
  }

  // ---- epilogue: C/D layout col=lane&15, row=(lane>>4)*4+j ----
#pragma unroll
  for (int mf = 0; mf < 8; mf++) {
    size_t row0 = arow0 + wm * 128 + mf * 16 + lg * 4;
#pragma unroll
    for (int nf = 0; nf < 4; nf++) {
      size_t col = brow0 + wn * 64 + nf * 16 + lr;
#pragma unroll
      for (int j = 0; j < 4; j++)
        C[(row0 + j) * N + col] = (OutT)acc[mf][nf][j];
    }
  }
}

// ----------------------------- attention -----------------------------------
#define STRD 72

__global__ __launch_bounds__(256) void hilbert_attn(
    const _Float16* __restrict__ qkv, _Float16* __restrict__ aout) {
  __shared__ _Float16 Qs[128 * STRD];
  __shared__ _Float16 Ks[64 * STRD];
  __shared__ _Float16 Vt[64 * STRD];  // transposed: Vt[d][j] = V[j][d]
  __shared__ _Float16 Ps[128 * STRD];
  const int blk = blockIdx.x;
  const int s = blk & 31, h = (blk >> 5) & 15, b = blk >> 9;
  const int t = threadIdx.x, lane = t & 63, wave = t >> 6;
  const int lr = lane & 15, lg = lane >> 4, lk = lg * 8;
  const size_t base = (size_t)b * 4096 * 3072;
  const int col = (t & 7) * 8, rr = t >> 3;

#pragma unroll
  for (int i = 0; i < 4; i++) {
    int m = i * 32 + rr;
    int p = hperm(s * 128 + m);
    *(f16x8*)&Qs[m * STRD + col] =
        *(const f16x8*)&qkv[base + (size_t)p * 3072 + h * 64 + col];
  }
#pragma unroll
  for (int i = 0; i < 2; i++) {
    int j = i * 32 + rr;
    int p = hperm(s * 128 + 2 * j);
    *(f16x8*)&Ks[j * STRD + col] =
        *(const f16x8*)&qkv[base + (size_t)p * 3072 + 1024 + h * 64 + col];
    f16x8 vv = *(const f16x8*)&qkv[base + (size_t)p * 3072 + 2048 + h * 64 + col];
#pragma unroll
    for (int e = 0; e < 8; e++) Vt[(col + e) * STRD + j] = vv[e];
  }
  __syncthreads();

  f32x4 accs[2][4] = {};
#pragma unroll
  for (int kk = 0; kk < 2; kk++) {
    f16x8 aa[2], bb[4];
#pragma unroll
    for (int m = 0; m < 2; m++)
      aa[m] = *(const f16x8*)&Qs[(wave * 32 + m * 16 + lr) * STRD + kk * 32 + lk];
#pragma unroll
    for (int n = 0; n < 4; n++)
      bb[n] = *(const f16x8*)&Ks[(n * 16 + lr) * STRD + kk * 32 + lk];
#pragma unroll
    for (int m = 0; m < 2; m++)
#pragma unroll
      for (int n = 0; n < 4; n++)
        accs[m][n] =
            __builtin_amdgcn_mfma_f32_16x16x32_f16(aa[m], bb[n], accs[m][n], 0, 0, 0);
  }

#pragma unroll
  for (int m = 0; m < 2; m++) {
#pragma unroll
    for (int j = 0; j < 4; j++) {
      float sc0 = accs[m][0][j] * 0.125f;
      float sc1 = accs[m][1][j] * 0.125f;
      float sc2 = accs[m][2][j] * 0.125f;
      float sc3 = accs[m][3][j] * 0.125f;
      float mx = fmaxf(fmaxf(sc0, sc1), fmaxf(sc2, sc3));
#pragma unroll
      for (int d = 1; d < 16; d <<= 1) mx = fmaxf(mx, __shfl_xor(mx, d, 16));
      float e0 = __expf(sc0 - mx), e1 = __expf(sc1 - mx);
      float e2 = __expf(sc2 - mx), e3 = __expf(sc3 - mx);
      float sum = (e0 + e1) + (e2 + e3);
#pragma unroll
      for (int d = 1; d < 16; d <<= 1) sum += __shfl_xor(sum, d, 16);
      float inv = 1.0f / sum;
      int row = wave * 32 + m * 16 + lg * 4 + j;
      Ps[row * STRD + 0 * 16 + lr] = (_Float16)(e0 * inv);
      Ps[row * STRD + 1 * 16 + lr] = (_Float16)(e1 * inv);
      Ps[row * STRD + 2 * 16 + lr] = (_Float16)(e2 * inv);
      Ps[row * STRD + 3 * 16 + lr] = (_Float16)(e3 * inv);
    }
  }
  __syncthreads();

  f32x4 acco[2][4] = {};
#pragma unroll
  for (int kk = 0; kk < 2; kk++) {
    f16x8 aa[2], bb[4];
#pragma unroll
    for (int m = 0; m < 2; m++)
      aa[m] = *(const f16x8*)&Ps[(wave * 32 + m * 16 + lr) * STRD + kk * 32 + lk];
#pragma unroll
    for (int n = 0; n < 4; n++)
      bb[n] = *(const f16x8*)&Vt[(n * 16 + lr) * STRD + kk * 32 + lk];
#pragma unroll
    for (int m = 0; m < 2; m++)
#pragma unroll
      for (int n = 0; n < 4; n++)
        acco[m][n] =
            __builtin_amdgcn_mfma_f32_16x16x32_f16(aa[m], bb[n], acco[m][n], 0, 0, 0);
  }

  const size_t orow0 = (size_t)b * 4096 + s * 128;
#pragma unroll
  for (int m = 0; m < 2; m++) {
#pragma unroll
    for (int n = 0; n < 4; n++) {
#pragma unroll
      for (int j = 0; j < 4; j++) {
        size_t row = orow0 + wave * 32 + m * 16 + lg * 4 + j;
        aout[row * 1024 + h * 64 + n * 16 + lr] = (_Float16)acco[m][n][j];
      }
    }
  }
}

// ---------------------------------------------------------------------------
extern "C" void kernel_launch(void* const* d_in, const int* in_sizes, int n_in,
                              void* d_out, int out_size, void* d_ws, size_t ws_size,
                              hipStream_t stream) {
  const float* x = (const float*)d_in[0];      // (4,4096,1024)
  const float* w_qkv = (const float*)d_in[1];  // (3072,1024)
  const float* w_out = (const float*)d_in[2];  // (1024,1024)
  float* out = (float*)d_out;                  // (4,4096,1024) fp32
  char* ws = (char*)d_ws;

  _Float16* xh = (_Float16*)(ws + 0);                    // 33,554,432 B
  _Float16* wqh = (_Float16*)(ws + (size_t)33554432);    //  6,291,456 B
  _Float16* woh = (_Float16*)(ws + (size_t)39845888);    //  2,097,152 B
  _Float16* qkvh = (_Float16*)(ws + (size_t)41943040);   // 100,663,296 B
  _Float16* atth = (_Float16*)(ws + (size_t)142606336);  // 33,554,432 B

  cast_f32_f16<<<16384, 256, 0, stream>>>(x, xh, 4194304);
  cast_f32_f16<<<3072, 256, 0, stream>>>(w_qkv, wqh, 786432);
  cast_f32_f16<<<1024, 256, 0, stream>>>(w_out, woh, 262144);

  // M=16384 -> 64 row-tiles; N=3072 -> 12 col-tiles (768 wg); N=1024 -> 4 (256 wg)
  gemm_nt_8ph<_Float16><<<768, 512, 0, stream>>>(xh, wqh, qkvh, 3072, 1024, 12);
  hilbert_attn<<<2048, 256, 0, stream>>>(qkvh, atth);
  gemm_nt_8ph<float><<<256, 512, 0, stream>>>(atth, woh, out, 1024, 1024, 4);
}

// Round 3
// 173.071 us; speedup vs baseline: 1.5026x; 1.2002x over previous
//
#include <hip/hip_runtime.h>

// ---------------------------------------------------------------------------
// HilbertAttention: Q-proj + dilation-packed KV-proj (fp16 MFMA, 256^2
// 8-phase) -> segmented attention -> out-proj.
// B=4, M=4096, D=1024, H=16, hd=64, SEG=128, DIL=2 -> S=32.
// perm is closed-form serpentine (g==64). Output stays in permuted row order.
// Key: only even within-segment K/V positions are used (DIL=2) -> KV-GEMM
// computes just those 8192 rows (gathered A staging via per-lane gload_lds
// source), written packed so attention reads K/V contiguously.
// ---------------------------------------------------------------------------

typedef _Float16 f16x8 __attribute__((ext_vector_type(8)));
typedef _Float16 f16x4 __attribute__((ext_vector_type(4)));
typedef float f32x4 __attribute__((ext_vector_type(4)));

__device__ __forceinline__ int hperm(int i) {
  int r = i >> 6, c = i & 63;
  return (r << 6) | ((r & 1) ? (63 - c) : c);
}

// A'-row m' -> x-row for the KV gather: m' = b*2048 + s*64 + j  ->
// b*4096 + hperm(s*128 + 2j)
__device__ __forceinline__ int arow_gather(int mp) {
  int b = mp >> 11, i = mp & 2047;
  int s = i >> 6, j = i & 63;
  return b * 4096 + hperm(s * 128 + 2 * j);
}

__device__ __forceinline__ void gload_lds16(const _Float16* g, _Float16* l) {
  __builtin_amdgcn_global_load_lds(
      (const __attribute__((address_space(1))) void*)g,
      (__attribute__((address_space(3))) void*)l, 16, 0, 0);
}

// -------------------------- cast fp32 -> fp16 ------------------------------
__global__ __launch_bounds__(256) void cast_f32_f16(
    const float* __restrict__ s, _Float16* __restrict__ d, int n4) {
  int i = blockIdx.x * 256 + threadIdx.x;
  if (i >= n4) return;
  float4 v = ((const float4*)s)[i];
  f16x4 o;
  o[0] = (_Float16)v.x;
  o[1] = (_Float16)v.y;
  o[2] = (_Float16)v.z;
  o[3] = (_Float16)v.w;
  *(f16x4*)&d[(size_t)i * 4] = o;
}

// ---------------- 256x256 8-phase NT GEMM: C = A * B^T ---------------------
// BK=64, 512 thr = 8 waves (2Mx4N), per-wave 128x64 out. LDS 128 KiB.
// Swizzle: 16B-slot XOR ((row&7)<<3 halves); 2-way conflicts = free.
// Stage slots: P0/P1 = A(k+1)->buf1; P2..P5 = B,B,A,A of (k+2)->buf0;
// P6/P7 = B(k+3)->buf1. vmcnt(4) only at P3/P7 (counted, never 0).

#define BAR __builtin_amdgcn_s_barrier()
#define LGKM0                                          \
  do {                                                 \
    asm volatile("s_waitcnt lgkmcnt(0)" ::: "memory"); \
    __builtin_amdgcn_sched_barrier(0);                 \
  } while (0)
#define VM4 asm volatile("s_waitcnt vmcnt(4)" ::: "memory")

#define STG(mat, kt, h, buf)                                          \
  do {                                                                \
    if ((kt) < NK) {                                                  \
      const _Float16* g0 = ((mat) ? gpB : gpA)[(h)*2] + (size_t)(kt)*64;   \
      const _Float16* g1 = ((mat) ? gpB : gpA)[(h)*2 + 1] + (size_t)(kt)*64; \
      _Float16* d_ = &lds[buf][mat][h][t * 8];                        \
      gload_lds16(g0, d_);                                            \
      gload_lds16(g1, d_ + 4096);                                     \
    }                                                                 \
  } while (0)

// fragment reads: precomputed bases + compile-time offsets (halves)
#define LDA_(buf, mh)                                            \
  _Pragma("unroll") for (int m = 0; m < 4; m++) {                \
    a[0][m] = *(const f16x8*)(aB[buf][0] + (mh)*4096 + m * 1024); \
    a[1][m] = *(const f16x8*)(aB[buf][1] + (mh)*4096 + m * 1024); \
  }

#define LDB_(buf, nh)                                                      \
  _Pragma("unroll") for (int nf = 0; nf < 2; nf++) {                       \
    b[nh][0][nf] = *(const f16x8*)(bB[buf][0] + (nh)*2048 + nf * 1024);    \
    b[nh][1][nf] = *(const f16x8*)(bB[buf][1] + (nh)*2048 + nf * 1024);    \
  }

#define MM_(mh, nh)                                                        \
  __builtin_amdgcn_s_setprio(1);                                           \
  _Pragma("unroll") for (int m = 0; m < 4; m++)                            \
      _Pragma("unroll") for (int nf = 0; nf < 2; nf++)                     \
          _Pragma("unroll") for (int ks = 0; ks < 2; ks++) acc[(mh)*4 + m] \
              [(nh)*2 + nf] = __builtin_amdgcn_mfma_f32_16x16x32_f16(      \
                  a[ks][m], b[nh][ks][nf], acc[(mh)*4 + m][(nh)*2 + nf],   \
                  0, 0, 0);                                                \
  __builtin_amdgcn_s_setprio(0);

template <typename OutT, bool GATHER>
__global__ __launch_bounds__(512, 2) void gemm_nt_8ph(
    const _Float16* __restrict__ A, const _Float16* __restrict__ B,
    OutT* __restrict__ C, int N, int K, int NB) {
  __shared__ _Float16 lds[2][2][2][8192];  // [dbuf][A/B][half][128*64]
  const int t = threadIdx.x;
  const int lane = t & 63, wave = t >> 6;
  const int wm = wave >> 2, wn = wave & 3;
  const int lr = lane & 15, lg = lane >> 4;

  // XCD-aware bijective swizzle (gridDim.x % 8 == 0 by construction)
  const int nwg = gridDim.x;
  const int id = blockIdx.x;
  const int sw = (id & 7) * (nwg >> 3) + (id >> 3);
  const int bn = sw % NB, bm = sw / NB;

  const size_t arow0 = (size_t)bm * 256;
  const size_t brow0 = (size_t)bn * 256;
  const int NK = K >> 6;

  // staging: thread t covers row (t>>3) + 64*r, swizzled source col
  const int sgrow = t >> 3;
  const int sgcol = ((t & 7) * 8) ^ ((sgrow & 7) << 3);
  const _Float16* gpA[4];
  const _Float16* gpB[4];
#pragma unroll
  for (int r = 0; r < 4; r++) {
    int mr = bm * 256 + 64 * r + sgrow;
    int ar = GATHER ? arow_gather(mr) : mr;
    gpA[r] = A + (size_t)ar * K + sgcol;
    gpB[r] = B + (brow0 + 64 * r + sgrow) * (size_t)K + sgcol;
  }

  // per-lane swizzled ds_read column offsets (row&7 == lr&7 for all frags)
  const int cx0 = (lg * 8) ^ ((lr & 7) << 3);
  const int cx1 = cx0 ^ 32;
  const _Float16* aB[2][2];
  const _Float16* bB[2][2];
#pragma unroll
  for (int bf = 0; bf < 2; bf++) {
    aB[bf][0] = &lds[bf][0][wm][lr * 64 + cx0];
    aB[bf][1] = &lds[bf][0][wm][lr * 64 + cx1];
    bB[bf][0] = &lds[bf][1][wn >> 1][(wn & 1) * 4096 + lr * 64 + cx0];
    bB[bf][1] = &lds[bf][1][wn >> 1][(wn & 1) * 4096 + lr * 64 + cx1];
  }

  f32x4 acc[8][4] = {};
  f16x8 a[2][4], b[2][2][2];

  // ---- prologue: k0 -> buf0 (A0,A1,B0,B1); k1.B0,B1 -> buf1 ----
  STG(0, 0, 0, 0);
  STG(0, 0, 1, 0);
  STG(1, 0, 0, 0);
  STG(1, 0, 1, 0);
  STG(1, 1, 0, 1);
  STG(1, 1, 1, 1);
  VM4;
  BAR;

  for (int i = 0; i < NK / 2; i++) {
    const int k1 = 2 * i + 1, k2 = 2 * i + 2, k3 = 2 * i + 3;
    // P0: compute buf0 (mh0,nh0)
    LDA_(0, 0); LDB_(0, 0); STG(0, k1, 0, 1); BAR; LGKM0; MM_(0, 0); BAR;
    // P1: (mh0,nh1)
    LDB_(0, 1);             STG(0, k1, 1, 1); BAR; LGKM0; MM_(0, 1); BAR;
    // P2: (mh1,nh1)
    LDA_(0, 1);             STG(1, k2, 0, 0); BAR; LGKM0; MM_(1, 1); BAR;
    // P3: (mh1,nh0)  [no ds_reads]
                            STG(1, k2, 1, 0); VM4; BAR; LGKM0; MM_(1, 0); BAR;
    // P4: compute buf1 (mh0,nh0)
    LDA_(1, 0); LDB_(1, 0); STG(0, k2, 0, 0); BAR; LGKM0; MM_(0, 0); BAR;
    // P5: (mh0,nh1)
    LDB_(1, 1);             STG(0, k2, 1, 0); BAR; LGKM0; MM_(0, 1); BAR;
    // P6: (mh1,nh1)
    LDA_(1, 1);             STG(1, k3, 0, 1); BAR; LGKM0; MM_(1, 1); BAR;
    // P7: (mh1,nh0)
                            STG(1, k3, 1, 1); VM4; BAR; LGKM0; MM_(1, 0); BAR;
  }

  // ---- epilogue: C/D layout col=lane&15, row=(lane>>4)*4+j ----
#pragma unroll
  for (int mf = 0; mf < 8; mf++) {
    size_t row0 = arow0 + wm * 128 + mf * 16 + lg * 4;
#pragma unroll
    for (int nf = 0; nf < 4; nf++) {
      size_t col = brow0 + wn * 64 + nf * 16 + lr;
#pragma unroll
      for (int j = 0; j < 4; j++)
        C[(row0 + j) * N + col] = (OutT)acc[mf][nf][j];
    }
  }
}

// ----------------------------- attention -----------------------------------
// One block per (b,h,s). Q gathered from qh via perm; K,V read CONTIGUOUSLY
// from the dilation-packed kvh[b*2048 + s*64 + j][2048] (K: col h*64+d,
// V: col 1024+h*64+d). LDS rows padded to stride 72 halves.
#define STRD 72

__global__ __launch_bounds__(256) void hilbert_attn(
    const _Float16* __restrict__ qh, const _Float16* __restrict__ kvh,
    _Float16* __restrict__ aout) {
  __shared__ _Float16 Qs[128 * STRD];
  __shared__ _Float16 Ks[64 * STRD];
  __shared__ _Float16 Vt[64 * STRD];  // transposed: Vt[d][j] = V[j][d]
  __shared__ _Float16 Ps[128 * STRD];
  const int blk = blockIdx.x;
  const int s = blk & 31, h = (blk >> 5) & 15, b = blk >> 9;
  const int t = threadIdx.x, lane = t & 63, wave = t >> 6;
  const int lr = lane & 15, lg = lane >> 4, lk = lg * 8;
  const int col = (t & 7) * 8, rr = t >> 3;
  const size_t kvb = ((size_t)b * 2048 + s * 64) * 2048;

#pragma unroll
  for (int i = 0; i < 4; i++) {
    int m = i * 32 + rr;
    int p = b * 4096 + hperm(s * 128 + m);
    *(f16x8*)&Qs[m * STRD + col] =
        *(const f16x8*)&qh[(size_t)p * 1024 + h * 64 + col];
  }
#pragma unroll
  for (int i = 0; i < 2; i++) {
    int j = i * 32 + rr;
    *(f16x8*)&Ks[j * STRD + col] =
        *(const f16x8*)&kvh[kvb + (size_t)j * 2048 + h * 64 + col];
    f16x8 vv =
        *(const f16x8*)&kvh[kvb + (size_t)j * 2048 + 1024 + h * 64 + col];
#pragma unroll
    for (int e = 0; e < 8; e++) Vt[(col + e) * STRD + j] = vv[e];
  }
  __syncthreads();

  f32x4 accs[2][4] = {};
#pragma unroll
  for (int kk = 0; kk < 2; kk++) {
    f16x8 aa[2], bb[4];
#pragma unroll
    for (int m = 0; m < 2; m++)
      aa[m] = *(const f16x8*)&Qs[(wave * 32 + m * 16 + lr) * STRD + kk * 32 + lk];
#pragma unroll
    for (int n = 0; n < 4; n++)
      bb[n] = *(const f16x8*)&Ks[(n * 16 + lr) * STRD + kk * 32 + lk];
#pragma unroll
    for (int m = 0; m < 2; m++)
#pragma unroll
      for (int n = 0; n < 4; n++)
        accs[m][n] =
            __builtin_amdgcn_mfma_f32_16x16x32_f16(aa[m], bb[n], accs[m][n], 0, 0, 0);
  }

#pragma unroll
  for (int m = 0; m < 2; m++) {
#pragma unroll
    for (int j = 0; j < 4; j++) {
      float sc0 = accs[m][0][j] * 0.125f;
      float sc1 = accs[m][1][j] * 0.125f;
      float sc2 = accs[m][2][j] * 0.125f;
      float sc3 = accs[m][3][j] * 0.125f;
      float mx = fmaxf(fmaxf(sc0, sc1), fmaxf(sc2, sc3));
#pragma unroll
      for (int d = 1; d < 16; d <<= 1) mx = fmaxf(mx, __shfl_xor(mx, d, 16));
      float e0 = __expf(sc0 - mx), e1 = __expf(sc1 - mx);
      float e2 = __expf(sc2 - mx), e3 = __expf(sc3 - mx);
      float sum = (e0 + e1) + (e2 + e3);
#pragma unroll
      for (int d = 1; d < 16; d <<= 1) sum += __shfl_xor(sum, d, 16);
      float inv = 1.0f / sum;
      int row = wave * 32 + m * 16 + lg * 4 + j;
      Ps[row * STRD + 0 * 16 + lr] = (_Float16)(e0 * inv);
      Ps[row * STRD + 1 * 16 + lr] = (_Float16)(e1 * inv);
      Ps[row * STRD + 2 * 16 + lr] = (_Float16)(e2 * inv);
      Ps[row * STRD + 3 * 16 + lr] = (_Float16)(e3 * inv);
    }
  }
  __syncthreads();

  f32x4 acco[2][4] = {};
#pragma unroll
  for (int kk = 0; kk < 2; kk++) {
    f16x8 aa[2], bb[4];
#pragma unroll
    for (int m = 0; m < 2; m++)
      aa[m] = *(const f16x8*)&Ps[(wave * 32 + m * 16 + lr) * STRD + kk * 32 + lk];
#pragma unroll
    for (int n = 0; n < 4; n++)
      bb[n] = *(const f16x8*)&Vt[(n * 16 + lr) * STRD + kk * 32 + lk];
#pragma unroll
    for (int m = 0; m < 2; m++)
#pragma unroll
      for (int n = 0; n < 4; n++)
        acco[m][n] =
            __builtin_amdgcn_mfma_f32_16x16x32_f16(aa[m], bb[n], acco[m][n], 0, 0, 0);
  }

  const size_t orow0 = (size_t)b * 4096 + s * 128;
#pragma unroll
  for (int m = 0; m < 2; m++) {
#pragma unroll
    for (int n = 0; n < 4; n++) {
#pragma unroll
      for (int j = 0; j < 4; j++) {
        size_t row = orow0 + wave * 32 + m * 16 + lg * 4 + j;
        aout[row * 1024 + h * 64 + n * 16 + lr] = (_Float16)acco[m][n][j];
      }
    }
  }
}

// ---------------------------------------------------------------------------
extern "C" void kernel_launch(void* const* d_in, const int* in_sizes, int n_in,
                              void* d_out, int out_size, void* d_ws, size_t ws_size,
                              hipStream_t stream) {
  const float* x = (const float*)d_in[0];      // (4,4096,1024)
  const float* w_qkv = (const float*)d_in[1];  // (3072,1024)
  const float* w_out = (const float*)d_in[2];  // (1024,1024)
  float* out = (float*)d_out;                  // (4,4096,1024) fp32
  char* ws = (char*)d_ws;

  _Float16* xh = (_Float16*)(ws + 0);                    // 33,554,432 B
  _Float16* wqh = (_Float16*)(ws + (size_t)33554432);    //  6,291,456 B
  _Float16* woh = (_Float16*)(ws + (size_t)39845888);    //  2,097,152 B
  _Float16* qh = (_Float16*)(ws + (size_t)41943040);     // 33,554,432 B
  _Float16* kvh = (_Float16*)(ws + (size_t)75497472);    // 33,554,432 B
  _Float16* atth = (_Float16*)(ws + (size_t)109051904);  // 33,554,432 B

  cast_f32_f16<<<16384, 256, 0, stream>>>(x, xh, 4194304);
  cast_f32_f16<<<3072, 256, 0, stream>>>(w_qkv, wqh, 786432);
  cast_f32_f16<<<1024, 256, 0, stream>>>(w_out, woh, 262144);

  // Q-proj: 16384 x 1024 x 1024, grid 64x4 = 256 wg (1 round)
  gemm_nt_8ph<_Float16, false><<<256, 512, 0, stream>>>(xh, wqh, qh,
                                                        1024, 1024, 4);
  // KV-proj (gathered even rows, packed): 8192 x 2048 x 1024, grid 32x8 = 256
  gemm_nt_8ph<_Float16, true><<<256, 512, 0, stream>>>(
      xh, wqh + (size_t)1024 * 1024, kvh, 2048, 1024, 8);
  hilbert_attn<<<2048, 256, 0, stream>>>(qh, kvh, atth);
  // out-proj: 16384 x 1024 x 1024
  gemm_nt_8ph<float, false><<<256, 512, 0, stream>>>(atth, woh, out,
                                                     1024, 1024, 4);
}

// Round 4
// 161.154 us; speedup vs baseline: 1.6137x; 1.0739x over previous
//
#include <hip/hip_runtime.h>

// ---------------------------------------------------------------------------
// HilbertAttention: fused cast -> fused {Q-proj | dilation-packed KV-proj}
// (fp16 MFMA, 256^2 8-phase) -> segmented attention -> out-proj.
// B=4, M=4096, D=1024, H=16, hd=64, SEG=128, DIL=2 -> S=32.
// perm is closed-form serpentine (g==64). Output stays in permuted row order.
// Only even within-segment K/V positions are used (DIL=2) -> KV-GEMM computes
// just those 8192 rows (gathered A staging), written dilation-packed.
// All GEMMs have K=1024 (NK=16). Tail iteration peeled with vmcnt(0) to fix
// the latent staging race when the last iteration skips its STG slots.
// ---------------------------------------------------------------------------

typedef _Float16 f16x8 __attribute__((ext_vector_type(8)));
typedef _Float16 f16x4 __attribute__((ext_vector_type(4)));
typedef float f32x4 __attribute__((ext_vector_type(4)));

__device__ __forceinline__ int hperm(int i) {
  int r = i >> 6, c = i & 63;
  return (r << 6) | ((r & 1) ? (63 - c) : c);
}

// A'-row m' -> x-row for the KV gather: m' = b*2048 + s*64 + j  ->
// b*4096 + hperm(s*128 + 2j)
__device__ __forceinline__ int arow_gather(int mp) {
  int b = mp >> 11, i = mp & 2047;
  int s = i >> 6, j = i & 63;
  return b * 4096 + hperm(s * 128 + 2 * j);
}

__device__ __forceinline__ void gload_lds16(const _Float16* g, _Float16* l) {
  __builtin_amdgcn_global_load_lds(
      (const __attribute__((address_space(1))) void*)g,
      (__attribute__((address_space(3))) void*)l, 16, 0, 0);
}

// -------------------- fused cast fp32 -> fp16 (3 tensors) ------------------
__global__ __launch_bounds__(256) void cast_all(
    const float* __restrict__ x, _Float16* __restrict__ xh,
    const float* __restrict__ wq, _Float16* __restrict__ wqh,
    const float* __restrict__ wo, _Float16* __restrict__ woh) {
  int i = blockIdx.x * 256 + threadIdx.x;  // float4 index, total 5242880
  const float* s;
  _Float16* d;
  int j;
  if (i < 4194304) {
    s = x; d = xh; j = i;
  } else if (i < 4194304 + 786432) {
    s = wq; d = wqh; j = i - 4194304;
  } else {
    s = wo; d = woh; j = i - (4194304 + 786432);
  }
  float4 v = ((const float4*)s)[j];
  f16x4 o;
  o[0] = (_Float16)v.x;
  o[1] = (_Float16)v.y;
  o[2] = (_Float16)v.z;
  o[3] = (_Float16)v.w;
  *(f16x4*)&d[(size_t)j * 4] = o;
}

// ---------------- 256x256 8-phase NT GEMM body: C = A * B^T ----------------
// K=1024 (NK=16), BK=64, 512 thr = 8 waves (2Mx4N), per-wave 128x64 out.
// LDS 128 KiB. Swizzle: 16B-slot XOR ((row&7)<<3 halves).
// Stage slots: P0/P1 = A(k1)->buf1; P2..P5 = B,B,A,A of (k2)->buf0;
// P6/P7 = B(k3)->buf1. vmcnt(4) only at P3/P7 (counted, never 0 in loop).
// Final iteration peeled: no staging, vmcnt(0) at its P3.

#define BAR __builtin_amdgcn_s_barrier()
#define LGKM0                                          \
  do {                                                 \
    asm volatile("s_waitcnt lgkmcnt(0)" ::: "memory"); \
    __builtin_amdgcn_sched_barrier(0);                 \
  } while (0)
#define LGKM8 asm volatile("s_waitcnt lgkmcnt(8)" ::: "memory")
#define VM4 asm volatile("s_waitcnt vmcnt(4)" ::: "memory")
#define VM0 asm volatile("s_waitcnt vmcnt(0)" ::: "memory")

#define STG(mat, kt, h, buf)                                                 \
  do {                                                                       \
    const _Float16* g0 = ((mat) ? gpB : gpA)[(h)*2] + (size_t)(kt)*64;       \
    const _Float16* g1 = ((mat) ? gpB : gpA)[(h)*2 + 1] + (size_t)(kt)*64;   \
    _Float16* d_ = &lds[buf][mat][h][t * 8];                                 \
    gload_lds16(g0, d_);                                                     \
    gload_lds16(g1, d_ + 4096);                                              \
  } while (0)

#define LDA_(buf, mh)                                            \
  _Pragma("unroll") for (int m = 0; m < 4; m++) {                \
    a[0][m] = *(const f16x8*)(aB[buf][0] + (mh)*4096 + m * 1024); \
    a[1][m] = *(const f16x8*)(aB[buf][1] + (mh)*4096 + m * 1024); \
  }

#define LDB_(buf, nh)                                                   \
  _Pragma("unroll") for (int nf = 0; nf < 2; nf++) {                    \
    b[nh][0][nf] = *(const f16x8*)(bB[buf][0] + (nh)*2048 + nf * 1024); \
    b[nh][1][nf] = *(const f16x8*)(bB[buf][1] + (nh)*2048 + nf * 1024); \
  }

#define MM_(mh, nh)                                                        \
  __builtin_amdgcn_s_setprio(1);                                           \
  _Pragma("unroll") for (int m = 0; m < 4; m++)                            \
      _Pragma("unroll") for (int nf = 0; nf < 2; nf++)                     \
          _Pragma("unroll") for (int ks = 0; ks < 2; ks++) acc[(mh)*4 + m] \
              [(nh)*2 + nf] = __builtin_amdgcn_mfma_f32_16x16x32_f16(      \
                  a[ks][m], b[nh][ks][nf], acc[(mh)*4 + m][(nh)*2 + nf],   \
                  0, 0, 0);                                                \
  __builtin_amdgcn_s_setprio(0);

template <typename OutT>
__device__ __forceinline__ void gemm_body(
    const _Float16* const* gpA, const _Float16* const* gpB,
    OutT* __restrict__ C, int N, size_t arow0, size_t brow0,
    _Float16 (&lds)[2][2][2][8192]) {
  const int t = threadIdx.x;
  const int lane = t & 63, wave = t >> 6;
  const int wm = wave >> 2, wn = wave & 3;
  const int lr = lane & 15, lg = lane >> 4;

  const int cx0 = (lg * 8) ^ ((lr & 7) << 3);
  const int cx1 = cx0 ^ 32;
  const _Float16* aB[2][2];
  const _Float16* bB[2][2];
#pragma unroll
  for (int bf = 0; bf < 2; bf++) {
    aB[bf][0] = &lds[bf][0][wm][lr * 64 + cx0];
    aB[bf][1] = &lds[bf][0][wm][lr * 64 + cx1];
    bB[bf][0] = &lds[bf][1][wn >> 1][(wn & 1) * 4096 + lr * 64 + cx0];
    bB[bf][1] = &lds[bf][1][wn >> 1][(wn & 1) * 4096 + lr * 64 + cx1];
  }

  f32x4 acc[8][4] = {};
  f16x8 a[2][4], b[2][2][2];

  // ---- prologue: k0 -> buf0 (A0,A1,B0,B1); k1.B0,B1 -> buf1 ----
  STG(0, 0, 0, 0);
  STG(0, 0, 1, 0);
  STG(1, 0, 0, 0);
  STG(1, 0, 1, 0);
  STG(1, 1, 0, 1);
  STG(1, 1, 1, 1);
  VM4;
  BAR;

  // ---- steady loop: 7 iterations (k-tiles 0..13), full staging ----
  for (int i = 0; i < 7; i++) {
    const int k1 = 2 * i + 1, k2 = 2 * i + 2, k3 = 2 * i + 3;
    LDA_(0, 0); LDB_(0, 0); STG(0, k1, 0, 1); LGKM8; BAR; LGKM0; MM_(0, 0); BAR;
    LDB_(0, 1);             STG(0, k1, 1, 1);        BAR; LGKM0; MM_(0, 1); BAR;
    LDA_(0, 1);             STG(1, k2, 0, 0);        BAR; LGKM0; MM_(1, 1); BAR;
                            STG(1, k2, 1, 0); VM4;   BAR; LGKM0; MM_(1, 0); BAR;
    LDA_(1, 0); LDB_(1, 0); STG(0, k2, 0, 0); LGKM8; BAR; LGKM0; MM_(0, 0); BAR;
    LDB_(1, 1);             STG(0, k2, 1, 0);        BAR; LGKM0; MM_(0, 1); BAR;
    LDA_(1, 1);             STG(1, k3, 0, 1);        BAR; LGKM0; MM_(1, 1); BAR;
                            STG(1, k3, 1, 1); VM4;   BAR; LGKM0; MM_(1, 0); BAR;
  }

  // ---- peeled tail (k-tiles 14,15): stage only A(15); vmcnt(0) at P3 ----
  {
    LDA_(0, 0); LDB_(0, 0); STG(0, 15, 0, 1); LGKM8; BAR; LGKM0; MM_(0, 0); BAR;
    LDB_(0, 1);             STG(0, 15, 1, 1);        BAR; LGKM0; MM_(0, 1); BAR;
    LDA_(0, 1);                                      BAR; LGKM0; MM_(1, 1); BAR;
                                              VM0;   BAR; LGKM0; MM_(1, 0); BAR;
    LDA_(1, 0); LDB_(1, 0);                          BAR; LGKM0; MM_(0, 0); BAR;
    LDB_(1, 1);                                      BAR; LGKM0; MM_(0, 1); BAR;
    LDA_(1, 1);                                      BAR; LGKM0; MM_(1, 1); BAR;
                                                          LGKM0; MM_(1, 0);
  }

  // ---- epilogue: C/D layout col=lane&15, row=(lane>>4)*4+j ----
#pragma unroll
  for (int mf = 0; mf < 8; mf++) {
    size_t row0 = arow0 + wm * 128 + mf * 16 + lg * 4;
#pragma unroll
    for (int nf = 0; nf < 4; nf++) {
      size_t col = brow0 + wn * 64 + nf * 16 + lr;
#pragma unroll
      for (int j = 0; j < 4; j++)
        C[(row0 + j) * N + col] = (OutT)acc[mf][nf][j];
    }
  }
}

// ---- fused Q-proj (sw<256) + KV-proj (sw>=256) over a 512-wg grid ----
__global__ __launch_bounds__(512, 2) void gemm_qkv8(
    const _Float16* __restrict__ xh, const _Float16* __restrict__ wqh,
    _Float16* __restrict__ qh, _Float16* __restrict__ kvh) {
  __shared__ _Float16 lds[2][2][2][8192];
  const int t = threadIdx.x;
  const int id = blockIdx.x;
  const int sw = (id & 7) * (gridDim.x >> 3) + (id >> 3);
  const bool iskv = sw >= 256;
  const int wid = iskv ? sw - 256 : sw;
  const int N = iskv ? 2048 : 1024;
  const int bn = iskv ? (wid & 7) : (wid & 3);
  const int bm = iskv ? (wid >> 3) : (wid >> 2);
  const _Float16* Bw = wqh + (iskv ? (size_t)1048576 : 0);
  _Float16* C = iskv ? kvh : qh;

  const int sgrow = t >> 3;
  const int sgcol = ((t & 7) * 8) ^ ((sgrow & 7) << 3);
  const _Float16* gpA[4];
  const _Float16* gpB[4];
#pragma unroll
  for (int r = 0; r < 4; r++) {
    int mr = bm * 256 + 64 * r + sgrow;
    int ar = iskv ? arow_gather(mr) : mr;
    gpA[r] = xh + (size_t)ar * 1024 + sgcol;
    gpB[r] = Bw + ((size_t)bn * 256 + 64 * r + sgrow) * 1024 + sgcol;
  }
  gemm_body<_Float16>(gpA, gpB, C, N, (size_t)bm * 256, (size_t)bn * 256, lds);
}

// ---- out-proj: 16384 x 1024 x 1024, fp32 output ----
__global__ __launch_bounds__(512, 2) void gemm_out8(
    const _Float16* __restrict__ atth, const _Float16* __restrict__ woh,
    float* __restrict__ out) {
  __shared__ _Float16 lds[2][2][2][8192];
  const int t = threadIdx.x;
  const int id = blockIdx.x;
  const int sw = (id & 7) * (gridDim.x >> 3) + (id >> 3);
  const int bn = sw & 3, bm = sw >> 2;

  const int sgrow = t >> 3;
  const int sgcol = ((t & 7) * 8) ^ ((sgrow & 7) << 3);
  const _Float16* gpA[4];
  const _Float16* gpB[4];
#pragma unroll
  for (int r = 0; r < 4; r++) {
    gpA[r] = atth + ((size_t)bm * 256 + 64 * r + sgrow) * 1024 + sgcol;
    gpB[r] = woh + ((size_t)bn * 256 + 64 * r + sgrow) * 1024 + sgcol;
  }
  gemm_body<float>(gpA, gpB, out, 1024, (size_t)bm * 256, (size_t)bn * 256,
                   lds);
}

// ----------------------------- attention -----------------------------------
// One block per (b,h,s). Q gathered from qh via perm; K,V read CONTIGUOUSLY
// from the dilation-packed kvh[b*2048 + s*64 + j][2048].
#define STRD 72

__global__ __launch_bounds__(256) void hilbert_attn(
    const _Float16* __restrict__ qh, const _Float16* __restrict__ kvh,
    _Float16* __restrict__ aout) {
  __shared__ _Float16 Qs[128 * STRD];
  __shared__ _Float16 Ks[64 * STRD];
  __shared__ _Float16 Vt[64 * STRD];  // transposed: Vt[d][j] = V[j][d]
  __shared__ _Float16 Ps[128 * STRD];
  const int blk = blockIdx.x;
  const int s = blk & 31, h = (blk >> 5) & 15, b = blk >> 9;
  const int t = threadIdx.x, lane = t & 63, wave = t >> 6;
  const int lr = lane & 15, lg = lane >> 4, lk = lg * 8;
  const int col = (t & 7) * 8, rr = t >> 3;
  const size_t kvb = ((size_t)b * 2048 + s * 64) * 2048;

#pragma unroll
  for (int i = 0; i < 4; i++) {
    int m = i * 32 + rr;
    int p = b * 4096 + hperm(s * 128 + m);
    *(f16x8*)&Qs[m * STRD + col] =
        *(const f16x8*)&qh[(size_t)p * 1024 + h * 64 + col];
  }
#pragma unroll
  for (int i = 0; i < 2; i++) {
    int j = i * 32 + rr;
    *(f16x8*)&Ks[j * STRD + col] =
        *(const f16x8*)&kvh[kvb + (size_t)j * 2048 + h * 64 + col];
    f16x8 vv =
        *(const f16x8*)&kvh[kvb + (size_t)j * 2048 + 1024 + h * 64 + col];
#pragma unroll
    for (int e = 0; e < 8; e++) Vt[(col + e) * STRD + j] = vv[e];
  }
  __syncthreads();

  f32x4 accs[2][4] = {};
#pragma unroll
  for (int kk = 0; kk < 2; kk++) {
    f16x8 aa[2], bb[4];
#pragma unroll
    for (int m = 0; m < 2; m++)
      aa[m] = *(const f16x8*)&Qs[(wave * 32 + m * 16 + lr) * STRD + kk * 32 + lk];
#pragma unroll
    for (int n = 0; n < 4; n++)
      bb[n] = *(const f16x8*)&Ks[(n * 16 + lr) * STRD + kk * 32 + lk];
#pragma unroll
    for (int m = 0; m < 2; m++)
#pragma unroll
      for (int n = 0; n < 4; n++)
        accs[m][n] =
            __builtin_amdgcn_mfma_f32_16x16x32_f16(aa[m], bb[n], accs[m][n], 0, 0, 0);
  }

#pragma unroll
  for (int m = 0; m < 2; m++) {
#pragma unroll
    for (int j = 0; j < 4; j++) {
      float sc0 = accs[m][0][j] * 0.125f;
      float sc1 = accs[m][1][j] * 0.125f;
      float sc2 = accs[m][2][j] * 0.125f;
      float sc3 = accs[m][3][j] * 0.125f;
      float mx = fmaxf(fmaxf(sc0, sc1), fmaxf(sc2, sc3));
#pragma unroll
      for (int d = 1; d < 16; d <<= 1) mx = fmaxf(mx, __shfl_xor(mx, d, 16));
      float e0 = __expf(sc0 - mx), e1 = __expf(sc1 - mx);
      float e2 = __expf(sc2 - mx), e3 = __expf(sc3 - mx);
      float sum = (e0 + e1) + (e2 + e3);
#pragma unroll
      for (int d = 1; d < 16; d <<= 1) sum += __shfl_xor(sum, d, 16);
      float inv = 1.0f / sum;
      int row = wave * 32 + m * 16 + lg * 4 + j;
      Ps[row * STRD + 0 * 16 + lr] = (_Float16)(e0 * inv);
      Ps[row * STRD + 1 * 16 + lr] = (_Float16)(e1 * inv);
      Ps[row * STRD + 2 * 16 + lr] = (_Float16)(e2 * inv);
      Ps[row * STRD + 3 * 16 + lr] = (_Float16)(e3 * inv);
    }
  }
  __syncthreads();

  f32x4 acco[2][4] = {};
#pragma unroll
  for (int kk = 0; kk < 2; kk++) {
    f16x8 aa[2], bb[4];
#pragma unroll
    for (int m = 0; m < 2; m++)
      aa[m] = *(const f16x8*)&Ps[(wave * 32 + m * 16 + lr) * STRD + kk * 32 + lk];
#pragma unroll
    for (int n = 0; n < 4; n++)
      bb[n] = *(const f16x8*)&Vt[(n * 16 + lr) * STRD + kk * 32 + lk];
#pragma unroll
    for (int m = 0; m < 2; m++)
#pragma unroll
      for (int n = 0; n < 4; n++)
        acco[m][n] =
            __builtin_amdgcn_mfma_f32_16x16x32_f16(aa[m], bb[n], acco[m][n], 0, 0, 0);
  }

  const size_t orow0 = (size_t)b * 4096 + s * 128;
#pragma unroll
  for (int m = 0; m < 2; m++) {
#pragma unroll
    for (int n = 0; n < 4; n++) {
#pragma unroll
      for (int j = 0; j < 4; j++) {
        size_t row = orow0 + wave * 32 + m * 16 + lg * 4 + j;
        aout[row * 1024 + h * 64 + n * 16 + lr] = (_Float16)acco[m][n][j];
      }
    }
  }
}

// ---------------------------------------------------------------------------
extern "C" void kernel_launch(void* const* d_in, const int* in_sizes, int n_in,
                              void* d_out, int out_size, void* d_ws, size_t ws_size,
                              hipStream_t stream) {
  const float* x = (const float*)d_in[0];      // (4,4096,1024)
  const float* w_qkv = (const float*)d_in[1];  // (3072,1024)
  const float* w_out = (const float*)d_in[2];  // (1024,1024)
  float* out = (float*)d_out;                  // (4,4096,1024) fp32
  char* ws = (char*)d_ws;

  _Float16* xh = (_Float16*)(ws + 0);                    // 33,554,432 B
  _Float16* wqh = (_Float16*)(ws + (size_t)33554432);    //  6,291,456 B
  _Float16* woh = (_Float16*)(ws + (size_t)39845888);    //  2,097,152 B
  _Float16* qh = (_Float16*)(ws + (size_t)41943040);     // 33,554,432 B
  _Float16* kvh = (_Float16*)(ws + (size_t)75497472);    // 33,554,432 B
  _Float16* atth = (_Float16*)(ws + (size_t)109051904);  // 33,554,432 B

  // 5,242,880 float4s across the three tensors
  cast_all<<<20480, 256, 0, stream>>>(x, xh, w_qkv, wqh, w_out, woh);

  // fused Q-proj (256 wg) + KV-proj (256 wg)
  gemm_qkv8<<<512, 512, 0, stream>>>(xh, wqh, qh, kvh);
  hilbert_attn<<<2048, 256, 0, stream>>>(qh, kvh, atth);
  gemm_out8<<<256, 512, 0, stream>>>(atth, woh, out);
}